// Round 8
// baseline (6619.482 us; speedup 1.0000x reference)
//
#include <hip/hip_runtime.h>
#include <hip/hip_fp16.h>
#include <stdint.h>

// ---------------- problem constants ----------------
#define T_STEPS 1000
#define G4      1024
#define NOUT    100
#define NW      20
#define NTHM    512
#define NGROUPS 16      // batch groups of 8 rows
#define BT      8

// roles per group (16 WGs): 0-3 stage0 (L0 + head), 4-9 stage1, 10-15 stage2
// ---------------- ws layout (dword offsets) ----------------
// hbuf: [16 groups][3 layers][4 ring slots][8 rows][128 dw] (u64-accessed)
constexpr int    OFF_HBUF  = 0;
constexpr int    OFF_CNT   = OFF_HBUF + NGROUPS*3*4*8*128;   // 196608: [16][448]
constexpr int    OFF_HEADW = OFF_CNT + NGROUPS*448;          // 203776: [120][132]
constexpr int    OFF_HXB   = OFF_HEADW + 120*132;            // 219616: [120][3] f32
constexpr int    OFF_MISC  = OFF_HXB + 360;                  // 219976: [16 roles][3][4][64] f32
constexpr int    OFF_WREG  = OFF_MISC + 16*768;              // 232264: 1408 slots x 512
constexpr size_t WS_DW     = (size_t)OFF_WREG + 1408*512;    // 953,160 dw ~= 3.81 MB
constexpr size_t GOFF      = (size_t)128*1000*100;

__device__ __forceinline__ float sigf(float x)     { return 1.0f / (1.0f + __expf(-x)); }
__device__ __forceinline__ float tanhfast(float x) { return 2.0f / (1.0f + __expf(-2.0f * x)) - 1.0f; }

typedef _Float16 h2v __attribute__((ext_vector_type(2)));
__device__ __forceinline__ float dot2f(uint32_t w, uint32_t h, float acc) {
    return __builtin_amdgcn_fdot2(__builtin_bit_cast(h2v, w),
                                  __builtin_bit_cast(h2v, h), acc, false);
}
__device__ __forceinline__ uint32_t pk(float a, float b) {
    __half2 h = __floats2half2_rn(a, b);
    return *reinterpret_cast<uint32_t*>(&h);
}
#define DPP_ADD(v, CTRL)                                                        \
    (v) += __builtin_bit_cast(float, __builtin_amdgcn_update_dpp(                \
              0, __builtin_bit_cast(int, (v)), (CTRL), 0xf, 0xf, true));

__device__ __forceinline__ void role_params(int rw, int& stage, int& idx, int& U, int& u0) {
    if (rw < 4)       { stage = 0; idx = rw;      U = 64;            u0 = 64*rw; }
    else if (rw < 10) { stage = 1; idx = rw - 4;  U = (idx<4)?44:40; u0 = (idx<=4)?44*idx:216; }
    else              { stage = 2; idx = rw - 10; U = (idx<4)?44:40; u0 = (idx<=4)?44*idx:216; }
}
__device__ __forceinline__ int role_off(int rw)   { return rw < 4 ? rw*64 : 256 + (rw-4)*96; }

__device__ __forceinline__ uint32_t fetch_wdw(int rw, int tid, int slot,
                                              const float* __restrict__ Whh0,
                                              const float* __restrict__ WihL,
                                              const float* __restrict__ WhhL) {
    int stage, idx, U, u0; role_params(rw, stage, idx, U, u0);
    int cq = tid >> 3, kq = tid & 7;
    int gate = cq >> 4, q = cq & 15;
    int mm, ul, d, u;
    if (stage == 0) { mm = 0; ul = slot >> 4; d = slot & 15; u = q*4 + ul; }
    else { mm = slot / 48; int rem = slot - mm*48; ul = rem >> 4; d = rem & 15; u = q*3 + ul;
           if (u >= U) return 0u; }
    int j = gate*256 + u0 + u;
    int k = kq*32 + 2*d;
    if (stage == 0) return pk(Whh0[(size_t)j*256 + k], Whh0[(size_t)j*256 + k + 1]);
    const float* Wi = WihL + (size_t)(stage-1)*G4*258;
    const float* Wh = WhhL + (size_t)(stage-1)*G4*256;
    if (mm == 0) return pk(Wi[(size_t)j*258 + 2 + k], Wi[(size_t)j*258 + 3 + k]);
    return pk(Wh[(size_t)j*256 + k], Wh[(size_t)j*256 + k + 1]);
}

// ---------------- prep kernels ----------------
__global__ void pack_wreg(const float* __restrict__ Whh0, const float* __restrict__ WihL,
                          const float* __restrict__ WhhL, uint32_t* __restrict__ wsd) {
    int slot = blockIdx.x % 96, rw = blockIdx.x / 96;   // grid 16*96
    if (rw < 4 && slot >= 64) return;
    wsd[OFF_WREG + (size_t)(role_off(rw) + slot)*512 + threadIdx.x] =
        fetch_wdw(rw, threadIdx.x, slot, Whh0, WihL, WhhL);
}

__global__ void pack_misc(const float* __restrict__ Wih0,
                          const float* __restrict__ bih0, const float* __restrict__ bhh0,
                          const float* __restrict__ WihL,
                          const float* __restrict__ bihL, const float* __restrict__ bhhL,
                          uint32_t* __restrict__ wsd) {
    int id = blockIdx.x * blockDim.x + threadIdx.x;
    if (id >= 16*768) return;
    int rw = id / 768, i = id % 768;
    int qq = i / 256, rem = i % 256, gate = rem / 64, u = rem % 64;
    int stage, idx, U, u0; role_params(rw, stage, idx, U, u0);
    float v = 0.0f;
    if (u < U) {
        int j = gate*256 + u0 + u;
        if (stage == 0)      v = (qq == 0) ? bih0[j] + bhh0[j] : Wih0[j*2 + (qq-1)];
        else if (stage == 1) v = (qq == 0) ? bihL[j] + bhhL[j] : WihL[(size_t)j*258 + (qq-1)];
        else                 v = (qq == 0) ? bihL[G4+j] + bhhL[G4+j]
                                           : WihL[(size_t)G4*258 + (size_t)j*258 + (qq-1)];
    }
    ((float*)wsd)[OFF_MISC + id] = v;
}

__global__ void pack_head(const float* __restrict__ Wg, const float* __restrict__ bg,
                          const float* __restrict__ Ww, const float* __restrict__ bw,
                          uint32_t* __restrict__ wsd) {
    int id = blockIdx.x * blockDim.x + threadIdx.x;
    if (id < 120*132) {
        int jo = id / 132, d = id % 132;
        uint32_t v = 0;
        if (d < 128) {
            int k = 2*d;
            const float* row = (jo < 100) ? (Wg + (size_t)jo*258) : (Ww + (size_t)(jo-100)*258);
            v = pk(row[2+k], row[3+k]);
        }
        wsd[OFF_HEADW + id] = v;
    } else if (id < 120*132 + 360) {
        int p = id - 120*132, jo = p/3, qq = p%3;
        const float* row = (jo < 100) ? (Wg + (size_t)jo*258) : (Ww + (size_t)(jo-100)*258);
        float v = (qq == 0) ? ((jo < 100) ? bg[jo] : bw[jo-100]) : row[qq-1];
        ((float*)wsd)[OFF_HXB + p] = v;
    }
}

__global__ void zero_cnt(uint32_t* __restrict__ wsd) {
    int id = blockIdx.x * blockDim.x + threadIdx.x;
    if (id < NGROUPS*448) wsd[OFF_CNT + id] = 0;
}

// ---------------- sync primitives ----------------
__device__ __forceinline__ void pollCnt(uint32_t* c, uint32_t tgt) {
    int spins = 0;
    while (__hip_atomic_load(c, __ATOMIC_RELAXED, __HIP_MEMORY_SCOPE_AGENT) < tgt) {
        __builtin_amdgcn_s_sleep(1);
        if (++spins > (1 << 24)) break;   // bailout: wrong answer beats a hang
    }
}
__device__ __forceinline__ void bump(uint32_t* c) {
    __hip_atomic_fetch_add(c, 1u, __ATOMIC_RELAXED, __HIP_MEMORY_SCOPE_AGENT);
}
// counters: PC_l at l*16; AC[class][slot] at (3 + class*4 + slot)*16
// classes: 0=h0-own(4 rdrs) 1=h0-skip(6) 2=h1-own(6) 3=h1-skip(6) 4=h2-own(6) 5=h2-head(4)
#define PCC(L)        (cnt + (L)*16)
#define ACC_(C, S)    (cnt + (3 + (C)*4 + (S))*16)

template<int NC, int BASE>
__device__ __forceinline__ void accum_mat(float* acc, const uint32_t (&wr)[96],
                                          const uint32_t* hb, int kq20) {
#pragma unroll
    for (int d4 = 0; d4 < 4; ++d4) {
        uint4 hv[8];
#pragma unroll
        for (int r = 0; r < 8; ++r)
            hv[r] = *(const uint4*)(hb + r*160 + kq20 + d4*4);
#pragma unroll
        for (int dd = 0; dd < 4; ++dd)
#pragma unroll
            for (int c = 0; c < NC; ++c) {
                uint32_t wv = wr[BASE + c*16 + d4*4 + dd];
#pragma unroll
                for (int r = 0; r < 8; ++r)
                    acc[c*8 + r] = dot2f(wv, ((const uint32_t*)&hv[r])[dd], acc[c*8 + r]);
            }
    }
}

#define READH(BUF, L, SLOT)                                                       \
    { int r_ = tid >> 6, i_ = tid & 63;                                           \
      uint64_t v_ = __hip_atomic_load(hbuf64 + (((L)*4 + (SLOT))*8 + r_)*64 + i_, \
                                      __ATOMIC_RELAXED, __HIP_MEMORY_SCOPE_AGENT);\
      *(uint64_t*)&h_lds[BUF][r_][(i_ >> 3)*20 + ((2*i_) & 15)] = v_; }

#define REDUCE_STORE(NC)                                                          \
    { _Pragma("unroll")                                                           \
      for (int i = 0; i < (NC)*8; ++i) {                                          \
          DPP_ADD(acc[i], 0x101) DPP_ADD(acc[i], 0x102) DPP_ADD(acc[i], 0x104)    \
      }                                                                           \
      if (kq == 0) {                                                              \
          _Pragma("unroll")                                                       \
          for (int c = 0; c < (NC); ++c) {                                        \
              int u_ = q*(NC) + c;                                                \
              if (u_ < U) { _Pragma("unroll")                                     \
                  for (int r = 0; r < 8; ++r) g_s[r][gate][u_] = acc[c*8 + r]; }  \
          } } }

// wave-per-row mapping: rr = tid>>6 (wave), uu = tid&63 -> stride-1 bank access
#define UPDATE_STORE(LYR, SLOT)                                                   \
    { float hval = 0.0f;                                                          \
      if (uu < U) {                                                               \
          float x0 = x_cur[rr][0], x1 = x_cur[rr][1];                             \
          float gi = g_s[rr][0][uu] + misc_s[0][0][uu] + x0*misc_s[1][0][uu] + x1*misc_s[2][0][uu]; \
          float gf = g_s[rr][1][uu] + misc_s[0][1][uu] + x0*misc_s[1][1][uu] + x1*misc_s[2][1][uu]; \
          float gg = g_s[rr][2][uu] + misc_s[0][2][uu] + x0*misc_s[1][2][uu] + x1*misc_s[2][2][uu]; \
          float go = g_s[rr][3][uu] + misc_s[0][3][uu] + x0*misc_s[1][3][uu] + x1*misc_s[2][3][uu]; \
          float cc_ = sigf(gf)*c_st + sigf(gi)*tanhfast(gg);                      \
          hval = sigf(go)*tanhfast(cc_);  c_st = cc_;                             \
      }                                                                           \
      float h1_ = __shfl_down(hval, 1), h2_ = __shfl_down(hval, 2), h3_ = __shfl_down(hval, 3); \
      if (uu < U && (uu & 3) == 0) {                                              \
          uint64_t pv = (uint64_t)pk(hval, h1_) | ((uint64_t)pk(h2_, h3_) << 32); \
          __hip_atomic_store(hbuf64 + (((LYR)*4 + (SLOT))*8 + rr)*64 + ((u0 + uu) >> 2), \
                             pv, __ATOMIC_RELAXED, __HIP_MEMORY_SCOPE_AGENT);     \
      } }

// all 512 threads participate; jol = tid>>4 in 0..31, masked by jol<30
#define HEAD_COMPUTE(TT, SLH)                                                     \
    { int jol = tid >> 4, rr2 = (tid >> 1) & 7, kh = tid & 1;                     \
      float acch = 0.0f;                                                          \
      if (jol < 30) {                                                             \
          _Pragma("unroll")                                                       \
          for (int blk = 0; blk < 4; ++blk)                                       \
              _Pragma("unroll")                                                   \
              for (int d4 = 0; d4 < 4; ++d4) {                                    \
                  uint4 wv = *(const uint4*)&headw_s[jol*132 + kh*64 + blk*16 + d4*4]; \
                  uint4 hv = *(const uint4*)&h_lds[1][rr2][(kh*4 + blk)*20 + d4*4];    \
                  acch = dot2f(wv.x, hv.x, acch); acch = dot2f(wv.y, hv.y, acch);      \
                  acch = dot2f(wv.z, hv.z, acch); acch = dot2f(wv.w, hv.w, acch);      \
              } }                                                                 \
      acch += __shfl_xor(acch, 1);                                                \
      if (jol < 30 && kh == 0) {                                                  \
          int jo = idx*30 + jol;                                                  \
          float xa = x_ring[SLH][rr2][0], xb = x_ring[SLH][rr2][1];               \
          acch += hxb_s[jol*3] + xa*hxb_s[jol*3+1] + xb*hxb_s[jol*3+2];           \
          if (jo < NOUT) out[((size_t)(b0 + rr2)*T_STEPS + (TT))*NOUT + jo] = acch; \
          else           wl_s[rr2][jo - NOUT] = acch;                             \
      }                                                                           \
      __syncthreads();                                                            \
      if (idx == 3 && tid < 8) {                                                  \
          int r = tid;                                                            \
          float mx = -1e30f;                                                      \
          _Pragma("unroll")                                                       \
          for (int m = 0; m < NW; ++m) mx = fmaxf(mx, wl_s[r][m]);                \
          float ss = 0.0f, ee[NW];                                                \
          _Pragma("unroll")                                                       \
          for (int m = 0; m < NW; ++m) { ee[m] = __expf(wl_s[r][m] - mx); ss += ee[m]; } \
          float inv = 1.0f / ss;                                                  \
          size_t bo = GOFF + ((size_t)(b0 + r)*T_STEPS + (TT))*NW;                \
          _Pragma("unroll")                                                       \
          for (int m = 0; m < NW; ++m) out[bo + m] = ee[m]*inv;                   \
      } }

template <bool WSPACK>
__global__ __launch_bounds__(NTHM, 2)
void lstm_pipe(const float* __restrict__ x, uint32_t* __restrict__ wsd,
               float* __restrict__ out,
               const float* __restrict__ Whh0, const float* __restrict__ WihL,
               const float* __restrict__ WhhL) {
    __shared__ __align__(16) uint32_t h_lds[2][8][160];
    __shared__ float    g_s[8][4][64];
    __shared__ float    misc_s[3][4][64];
    __shared__ float    x_cur[8][2];
    __shared__ float    x_ring[4][8][2];
    __shared__ __align__(16) uint32_t headw_s[30*132];
    __shared__ float    hxb_s[30*3];
    __shared__ float    wl_s[8][NW];

    const int tid = threadIdx.x;
    const int bid = blockIdx.x;
    const int g  = bid & (NGROUPS-1);
    const int rw = bid >> 4;
    int stage, idx, U, u0; role_params(rw, stage, idx, U, u0);
    const int b0 = g * BT;
    const int cq = tid >> 3, kq = tid & 7;
    const int gate = cq >> 4, q = cq & 15;
    const int kq20 = kq * 20;
    const int rr = tid >> 6, uu = tid & 63;   // update task (wave=row, lane=unit)

    uint64_t* hbuf64 = (uint64_t*)(wsd + OFF_HBUF) + (size_t)g * 6144;
    uint32_t* cnt = wsd + OFF_CNT + g * 448;
    const float* wsf = (const float*)wsd;

    // ---- persistent weights ----
    uint32_t wr[96];
    const int nslot = (rw < 4) ? 64 : 96;
    if (WSPACK) {
        const uint32_t* wb = wsd + OFF_WREG + (size_t)role_off(rw)*512 + tid;
#pragma unroll
        for (int i = 0; i < 96; ++i) wr[i] = (i < nslot) ? wb[(size_t)i*512] : 0u;
    } else {
#pragma unroll
        for (int i = 0; i < 96; ++i) wr[i] = (i < nslot) ? fetch_wdw(rw, tid, i, Whh0, WihL, WhhL) : 0u;
    }

    // ---- init LDS ----
    for (int i = tid; i < 2*8*160; i += NTHM) (&h_lds[0][0][0])[i] = 0u;
    for (int i = tid; i < 768;     i += NTHM) (&misc_s[0][0][0])[i] = wsf[OFF_MISC + rw*768 + i];
    if (stage == 0) {
        for (int i = tid; i < 30*132; i += NTHM) headw_s[i] = wsd[OFF_HEADW + idx*30*132 + i];
        for (int i = tid; i < 90;     i += NTHM) hxb_s[i]   = wsf[OFF_HXB + idx*90 + i];
    }
    float c_st = 0.0f;
    __syncthreads();

    float acc[32];

    if (stage == 0) {
        // =========== stage0: L0 (+ head trailing by 3) ===========
        for (int t = 0; t <= 1002; ++t) {
            const bool doL0 = (t < T_STEPS);
            const bool doHd = (t >= 3);
            const int th = t - 3;
            const int sl = t & 3, slp = (t - 1) & 3, slh = th & 3;
            float xv = 0.0f;
            if (doL0 && tid < 16)
                xv = x[((size_t)(b0 + (tid >> 1))*T_STEPS + t)*2 + (tid & 1)];
            if (tid == 0) {
                if (doL0 && t >= 1) pollCnt(PCC(0), 4u*(uint32_t)t);
                if (doL0 && t >= 4) { pollCnt(ACC_(0, sl), 4u*(uint32_t)(t >> 2));
                                      pollCnt(ACC_(1, sl), 6u*(uint32_t)(t >> 2)); }
                if (doHd)           pollCnt(PCC(2), 6u*(uint32_t)(t - 2));
            }
            __syncthreads();
            if (doL0 && t >= 1) READH(0, 0, slp)    // h0@(t-1)
            if (doHd)           READH(1, 2, slh)    // h2@(t-3)
            __syncthreads();
            if (tid == 0) {
                if (doL0 && t >= 1) bump(ACC_(0, slp));
                if (doHd)           bump(ACC_(5, slh));
            }
            if (doL0) {
#pragma unroll
                for (int i = 0; i < 32; ++i) acc[i] = 0.0f;
                accum_mat<4,0>(acc, wr, &h_lds[0][0][0], kq20);
                REDUCE_STORE(4)
                if (tid < 16) {
                    x_cur[tid >> 1][tid & 1] = xv;
                    x_ring[sl][tid >> 1][tid & 1] = xv;
                }
            }
            __syncthreads();
            if (doL0) UPDATE_STORE(0, sl)
            __syncthreads();
            if (tid == 0 && doL0) bump(PCC(0));
            if (doHd) HEAD_COMPUTE(th, slh)
        }
    } else {
        // =========== stage1 / stage2 ===========
        const int OWN_L = stage, IN_L = stage - 1;
        const int ownCls  = (stage == 1) ? 2 : 4;   // readers of own layer (recur), 6 members
        const int own2Cls = (stage == 1) ? 3 : 5;   // other readers of own layer
        const int inCls   = (stage == 1) ? 1 : 3;   // our ack class for the input layer
        const uint32_t OTH = (stage == 1) ? 6u : 4u;
        const uint32_t PIN = (stage == 1) ? 4u : 6u;
        for (int t = 0; t < T_STEPS; ++t) {
            const int sl = t & 3, slp = (t - 1) & 3;
            float xv = 0.0f;
            if (tid < 16)
                xv = x[((size_t)(b0 + (tid >> 1))*T_STEPS + t)*2 + (tid & 1)];
            if (tid == 0) {
                if (t >= 1) pollCnt(PCC(OWN_L), 6u*(uint32_t)t);          // own h@t-1
                if (t >= 4) { pollCnt(ACC_(ownCls, sl), 6u*(uint32_t)(t >> 2));
                              pollCnt(ACC_(own2Cls, sl), OTH*(uint32_t)(t >> 2)); }
            }
            __syncthreads();
            if (t >= 1) READH(1, OWN_L, slp)
            __syncthreads();
            if (tid == 0 && t >= 1) bump(ACC_(ownCls, slp));
#pragma unroll
            for (int i = 0; i < 24; ++i) acc[i] = 0.0f;
            accum_mat<3,48>(acc, wr, &h_lds[1][0][0], kq20);   // recur FIRST (hides skip wait)
            if (tid == 0) pollCnt(PCC(IN_L), PIN*(uint32_t)(t + 1));      // skip input h@t
            __syncthreads();
            READH(0, IN_L, sl)
            __syncthreads();
            if (tid == 0) bump(ACC_(inCls, sl));
            accum_mat<3,0>(acc, wr, &h_lds[0][0][0], kq20);    // skip matrix
            REDUCE_STORE(3)
            if (tid < 16) x_cur[tid >> 1][tid & 1] = xv;
            __syncthreads();
            UPDATE_STORE(OWN_L, sl)
            __syncthreads();
            if (tid == 0) bump(PCC(OWN_L));
        }
    }
}

extern "C" void kernel_launch(void* const* d_in, const int* in_sizes, int n_in,
                              void* d_out, int out_size, void* d_ws, size_t ws_size,
                              hipStream_t stream) {
    const float* x    = (const float*)d_in[0];
    const float* Wih0 = (const float*)d_in[1];
    const float* Whh0 = (const float*)d_in[2];
    const float* bih0 = (const float*)d_in[3];
    const float* bhh0 = (const float*)d_in[4];
    const float* WihL = (const float*)d_in[5];
    const float* WhhL = (const float*)d_in[6];
    const float* bihL = (const float*)d_in[7];
    const float* bhhL = (const float*)d_in[8];
    const float* Wg   = (const float*)d_in[9];
    const float* bg   = (const float*)d_in[10];
    const float* Ww   = (const float*)d_in[11];
    const float* bw   = (const float*)d_in[12];
    float*    out = (float*)d_out;
    uint32_t* wsd = (uint32_t*)d_ws;
    (void)in_sizes; (void)n_in; (void)out_size;

    const bool wspack = ws_size >= WS_DW * 4;

    zero_cnt<<<28, 256, 0, stream>>>(wsd);
    pack_misc<<<48, 256, 0, stream>>>(Wih0, bih0, bhh0, WihL, bihL, bhhL, wsd);
    pack_head<<<64, 256, 0, stream>>>(Wg, bg, Ww, bw, wsd);
    if (wspack)
        pack_wreg<<<16*96, 512, 0, stream>>>(Whh0, WihL, WhhL, wsd);

    dim3 grid(NGROUPS * 16), block(NTHM);
    void* args[] = {(void*)&x, (void*)&wsd, (void*)&out,
                    (void*)&Whh0, (void*)&WihL, (void*)&WhhL};
    if (wspack) {
        hipError_t err = hipLaunchCooperativeKernel((const void*)lstm_pipe<true>,
                                                    grid, block, args, 0, stream);
        if (err != hipSuccess)
            lstm_pipe<true><<<grid, block, 0, stream>>>(x, wsd, out, Whh0, WihL, WhhL);
    } else {
        hipError_t err = hipLaunchCooperativeKernel((const void*)lstm_pipe<false>,
                                                    grid, block, args, 0, stream);
        if (err != hipSuccess)
            lstm_pipe<false><<<grid, block, 0, stream>>>(x, wsd, out, Whh0, WihL, WhhL);
    }
}

// Round 9
// 4847.126 us; speedup vs baseline: 1.3657x; 1.3657x over previous
//
#include <hip/hip_runtime.h>
#include <hip/hip_fp16.h>
#include <stdint.h>

// ---------------- problem constants ----------------
#define T_STEPS 1000
#define G4      1024
#define NOUT    100
#define NW      20
#define NTHM    512
#define NGROUPS 8       // batch groups of 16 rows
#define BT      16

// roles per group (16 WGs): 0-3 stage0 (L0 + head), 4-9 stage1, 10-15 stage2
// ---------------- ws layout (dword offsets) ----------------
// hbuf: [8 groups][3 layers][4 slots][16 rows][64 u64]
constexpr int    OFF_HBUF  = 0;
constexpr int    OFF_CNT   = OFF_HBUF + NGROUPS*3*4*16*128;  // 196608: [8][448]
constexpr int    OFF_HEADW = OFF_CNT + NGROUPS*448;          // 200192: [120][132]
constexpr int    OFF_HXB   = OFF_HEADW + 120*132;            // 216032: [120][3] f32
constexpr int    OFF_MISC  = OFF_HXB + 360;                  // 216392: [16 roles][3][4][64] f32
constexpr int    OFF_WREG  = OFF_MISC + 16*768;              // 228680: [16 roles][32 slots][512 thr][4dw]
constexpr size_t WS_DW     = (size_t)OFF_WREG + (size_t)16*32*512*4;  // 1,277,256 dw ~= 5.1 MB
constexpr size_t GOFF      = (size_t)128*1000*100;

__device__ __forceinline__ float sigf(float x)     { return 1.0f / (1.0f + __expf(-x)); }
__device__ __forceinline__ float tanhfast(float x) { return 2.0f / (1.0f + __expf(-2.0f * x)) - 1.0f; }

typedef _Float16 h2v   __attribute__((ext_vector_type(2)));
typedef _Float16 f16x8v __attribute__((ext_vector_type(8)));
typedef float    f32x4v __attribute__((ext_vector_type(4)));
#define MFMA16(A, B, C) __builtin_amdgcn_mfma_f32_16x16x32_f16((A), (B), (C), 0, 0, 0)

__device__ __forceinline__ float dot2f(uint32_t w, uint32_t h, float acc) {
    return __builtin_amdgcn_fdot2(__builtin_bit_cast(h2v, w),
                                  __builtin_bit_cast(h2v, h), acc, false);
}
__device__ __forceinline__ uint32_t pk(float a, float b) {
    __half2 h = __floats2half2_rn(a, b);
    return *reinterpret_cast<uint32_t*>(&h);
}

__device__ __forceinline__ void role_params(int rw, int& stage, int& idx, int& U, int& u0) {
    if (rw < 4)       { stage = 0; idx = rw;      U = 64; u0 = 64*idx; }
    else if (rw < 10) { stage = 1; idx = rw - 4;  U = (idx < 4) ? 48 : 32;
                        u0 = (idx < 4) ? 48*idx : 192 + 32*(idx - 4); }
    else              { stage = 2; idx = rw - 10; U = (idx < 4) ? 48 : 32;
                        u0 = (idx < 4) ? 48*idx : 192 + 32*(idx - 4); }
}

// B-fragment weight dword for (role rw, thread tid, slot s = ntl*16+kt, dword d).
// wave=tid>>6, lane=tid&63. nt: wave<extra -> 2*wave+ntl else extra+wave (ntl==0).
// j = gate*256 + u0 + usub*16 + (lane&15); k = [kt or kt-8]*32 + (lane>>4)*8 + 2d.
// kt<8: stage0 Whh0 / stage1,2 skip Wih; kt>=8: recur Whh (stage0 unused).
__device__ __forceinline__ uint32_t fetch_wdw(int rw, int tid, int slot, int d,
                                              const float* __restrict__ Whh0,
                                              const float* __restrict__ WihL,
                                              const float* __restrict__ WhhL) {
    int stage, idx, U, u0; role_params(rw, stage, idx, U, u0);
    int wave = tid >> 6, lane = tid & 63;
    int NT = U >> 2, extra = NT - 8;
    int ntl = slot >> 4, kt = slot & 15;
    int nt;
    if (wave < extra) nt = 2*wave + ntl;
    else { if (ntl) return 0u; nt = extra + wave; }
    if (nt >= NT) return 0u;
    if (stage == 0 && kt >= 8) return 0u;
    int upg = U >> 4;
    int gate = nt / upg, usub = nt % upg;
    int j = gate*256 + u0 + usub*16 + (lane & 15);
    int khalf = lane >> 4;
    if (stage == 0) {
        int k = kt*32 + khalf*8 + 2*d;
        return pk(Whh0[(size_t)j*256 + k], Whh0[(size_t)j*256 + k + 1]);
    }
    if (kt < 8) {
        int k = kt*32 + khalf*8 + 2*d;
        const float* Wi = WihL + (size_t)(stage-1)*G4*258;
        return pk(Wi[(size_t)j*258 + 2 + k], Wi[(size_t)j*258 + 3 + k]);
    }
    int k = (kt-8)*32 + khalf*8 + 2*d;
    const float* Wh = WhhL + (size_t)(stage-1)*G4*256;
    return pk(Wh[(size_t)j*256 + k], Wh[(size_t)j*256 + k + 1]);
}

// ---------------- prep kernels ----------------
__global__ void pack_wreg(const float* __restrict__ Whh0, const float* __restrict__ WihL,
                          const float* __restrict__ WhhL, uint32_t* __restrict__ wsd) {
    int slot = blockIdx.x & 31, rw = blockIdx.x >> 5;   // grid 16*32
    int tid = threadIdx.x;
    uint32_t* dst = wsd + OFF_WREG + ((size_t)(rw*32 + slot)*512 + tid)*4;
    dst[0] = fetch_wdw(rw, tid, slot, 0, Whh0, WihL, WhhL);
    dst[1] = fetch_wdw(rw, tid, slot, 1, Whh0, WihL, WhhL);
    dst[2] = fetch_wdw(rw, tid, slot, 2, Whh0, WihL, WhhL);
    dst[3] = fetch_wdw(rw, tid, slot, 3, Whh0, WihL, WhhL);
}

__global__ void pack_misc(const float* __restrict__ Wih0,
                          const float* __restrict__ bih0, const float* __restrict__ bhh0,
                          const float* __restrict__ WihL,
                          const float* __restrict__ bihL, const float* __restrict__ bhhL,
                          uint32_t* __restrict__ wsd) {
    int id = blockIdx.x * blockDim.x + threadIdx.x;
    if (id >= 16*768) return;
    int rw = id / 768, i = id % 768;
    int qq = i / 256, rem = i % 256, gate = rem / 64, u = rem % 64;
    int stage, idx, U, u0; role_params(rw, stage, idx, U, u0);
    float v = 0.0f;
    if (u < U) {
        int j = gate*256 + u0 + u;
        if (stage == 0)      v = (qq == 0) ? bih0[j] + bhh0[j] : Wih0[j*2 + (qq-1)];
        else if (stage == 1) v = (qq == 0) ? bihL[j] + bhhL[j] : WihL[(size_t)j*258 + (qq-1)];
        else                 v = (qq == 0) ? bihL[G4+j] + bhhL[G4+j]
                                           : WihL[(size_t)G4*258 + (size_t)j*258 + (qq-1)];
    }
    ((float*)wsd)[OFF_MISC + id] = v;
}

__global__ void pack_head(const float* __restrict__ Wg, const float* __restrict__ bg,
                          const float* __restrict__ Ww, const float* __restrict__ bw,
                          uint32_t* __restrict__ wsd) {
    int id = blockIdx.x * blockDim.x + threadIdx.x;
    if (id < 120*132) {
        int jo = id / 132, d = id % 132;
        uint32_t v = 0;
        if (d < 128) {
            int k = 2*d;
            const float* row = (jo < 100) ? (Wg + (size_t)jo*258) : (Ww + (size_t)(jo-100)*258);
            v = pk(row[2+k], row[3+k]);
        }
        wsd[OFF_HEADW + id] = v;
    } else if (id < 120*132 + 360) {
        int p = id - 120*132, jo = p/3, qq = p%3;
        const float* row = (jo < 100) ? (Wg + (size_t)jo*258) : (Ww + (size_t)(jo-100)*258);
        float v = (qq == 0) ? ((jo < 100) ? bg[jo] : bw[jo-100]) : row[qq-1];
        ((float*)wsd)[OFF_HXB + p] = v;
    }
}

__global__ void zero_cnt(uint32_t* __restrict__ wsd) {
    int id = blockIdx.x * blockDim.x + threadIdx.x;
    if (id < NGROUPS*448) wsd[OFF_CNT + id] = 0;
}

// ---------------- sync primitives (r8, proven) ----------------
__device__ __forceinline__ void pollCnt(uint32_t* c, uint32_t tgt) {
    int spins = 0;
    while (__hip_atomic_load(c, __ATOMIC_RELAXED, __HIP_MEMORY_SCOPE_AGENT) < tgt) {
        __builtin_amdgcn_s_sleep(1);
        if (++spins > (1 << 24)) break;
    }
}
__device__ __forceinline__ void bump(uint32_t* c) {
    __hip_atomic_fetch_add(c, 1u, __ATOMIC_RELAXED, __HIP_MEMORY_SCOPE_AGENT);
}
// PC_l at l*16; AC[class][slot] at (3+class*4+slot)*16
// classes: 0=h0-own(4) 1=h0-skip(6) 2=h1-own(6) 3=h1-skip(6) 4=h2-own(6) 5=h2-head(4)
#define PCC(L)     (cnt + (L)*16)
#define ACC_(C, S) (cnt + (3 + (C)*4 + (S))*16)

// 8 MFMA k-steps over one 256-wide h operand (padded LDS rows of 132 dw)
template<int SO>
__device__ __forceinline__ void mfma8(f32x4v& ac0, f32x4v& ac1, const f16x8v (&wrf)[32],
                                      const uint32_t* hb, int rA, int khalf, bool nt2) {
#pragma unroll
    for (int kt = 0; kt < 8; ++kt) {
        uint4 hv = *(const uint4*)(hb + rA*132 + kt*16 + khalf*4);
        f16x8v a = __builtin_bit_cast(f16x8v, hv);
        ac0 = MFMA16(a, wrf[SO + kt], ac0);
        if (nt2) ac1 = MFMA16(a, wrf[16 + SO + kt], ac1);
    }
}

#define READH(BUF, L, SLOT)                                                        \
    { _Pragma("unroll")                                                            \
      for (int p_ = 0; p_ < 2; ++p_) {                                             \
        int idx_ = tid + p_*512;                                                   \
        int r_ = idx_ >> 6, i_ = idx_ & 63;                                        \
        uint64_t v_ = __hip_atomic_load(hbuf64 + (((L)*4 + (SLOT))*16 + r_)*64 + i_, \
                                        __ATOMIC_RELAXED, __HIP_MEMORY_SCOPE_AGENT); \
        *(uint64_t*)&h_lds[BUF][r_][2*i_] = v_;                                    \
      } }

#define DWRITE()                                                                   \
    { _Pragma("unroll")                                                            \
      for (int rg = 0; rg < 4; ++rg) g_s[m0 + rg][gate0][ul0] = ac0[rg];           \
      if (nt2) { _Pragma("unroll")                                                 \
          for (int rg = 0; rg < 4; ++rg) g_s[m0 + rg][gate1][ul1] = ac1[rg]; } }

#define UPDATE_PASS(PASS, CST, LYR, SLOT)                                          \
    { int r_ = tid & 15, u_ = (PASS)*32 + (tid >> 4);                              \
      float hval = 0.0f;                                                           \
      if (u_ < U) {                                                                \
          float x0 = x_cur[r_][0], x1 = x_cur[r_][1];                              \
          float gi = g_s[r_][0][u_] + misc_s[0][0][u_] + x0*misc_s[1][0][u_] + x1*misc_s[2][0][u_]; \
          float gf = g_s[r_][1][u_] + misc_s[0][1][u_] + x0*misc_s[1][1][u_] + x1*misc_s[2][1][u_]; \
          float gg = g_s[r_][2][u_] + misc_s[0][2][u_] + x0*misc_s[1][2][u_] + x1*misc_s[2][2][u_]; \
          float go = g_s[r_][3][u_] + misc_s[0][3][u_] + x0*misc_s[1][3][u_] + x1*misc_s[2][3][u_]; \
          float cc_ = sigf(gf)*(CST) + sigf(gi)*tanhfast(gg);                      \
          hval = sigf(go)*tanhfast(cc_);  (CST) = cc_;                             \
      }                                                                            \
      float h1_ = __shfl_down(hval, 16), h2_ = __shfl_down(hval, 32), h3_ = __shfl_down(hval, 48); \
      if ((tid & 63) < 16 && u_ < U) {                                             \
          uint64_t pv = (uint64_t)pk(hval, h1_) | ((uint64_t)pk(h2_, h3_) << 32);  \
          __hip_atomic_store(hbuf64 + (((LYR)*4 + (SLOT))*16 + r_)*64              \
                                 + (u0 >> 2) + (PASS)*8 + (tid >> 6), pv,          \
                             __ATOMIC_RELAXED, __HIP_MEMORY_SCOPE_AGENT);          \
      } }

#define HEAD_COMPUTE(TT, SLH)                                                      \
    { int jol = tid >> 4, rr2 = tid & 15;                                          \
      float acch = 0.0f;                                                           \
      if (jol < 30) {                                                              \
          _Pragma("unroll")                                                        \
          for (int d4 = 0; d4 < 32; ++d4) {                                        \
              uint4 wv = *(const uint4*)&headw_s[jol*132 + d4*4];                  \
              uint4 hv = *(const uint4*)&h_lds[1][rr2][d4*4];                      \
              acch = dot2f(wv.x, hv.x, acch); acch = dot2f(wv.y, hv.y, acch);      \
              acch = dot2f(wv.z, hv.z, acch); acch = dot2f(wv.w, hv.w, acch);      \
          }                                                                        \
          int jo = idx*30 + jol;                                                   \
          float xa = x_ring[SLH][rr2][0], xb = x_ring[SLH][rr2][1];                \
          acch += hxb_s[jol*3] + xa*hxb_s[jol*3+1] + xb*hxb_s[jol*3+2];            \
          if (jo < NOUT) out[((size_t)(b0 + rr2)*T_STEPS + (TT))*NOUT + jo] = acch; \
          else           wl_s[rr2][jo - NOUT] = acch;                              \
      }                                                                            \
      __syncthreads();                                                             \
      if (idx == 3 && tid < 16) {                                                  \
          int r = tid;                                                             \
          float mx = -1e30f;                                                       \
          _Pragma("unroll")                                                        \
          for (int m = 0; m < NW; ++m) mx = fmaxf(mx, wl_s[r][m]);                 \
          float ss = 0.0f, ee[NW];                                                 \
          _Pragma("unroll")                                                        \
          for (int m = 0; m < NW; ++m) { ee[m] = __expf(wl_s[r][m] - mx); ss += ee[m]; } \
          float inv = 1.0f / ss;                                                   \
          size_t bo = GOFF + ((size_t)(b0 + r)*T_STEPS + (TT))*NW;                 \
          _Pragma("unroll")                                                        \
          for (int m = 0; m < NW; ++m) out[bo + m] = ee[m]*inv;                    \
      } }

template <bool WSPACK>
__global__ __launch_bounds__(NTHM, 1)
void lstm_pipe(const float* __restrict__ x, uint32_t* __restrict__ wsd,
               float* __restrict__ out,
               const float* __restrict__ Whh0, const float* __restrict__ WihL,
               const float* __restrict__ WhhL) {
    __shared__ __align__(16) uint32_t h_lds[2][16][132];   // fp16-pair dw, padded stride
    __shared__ float    g_s[16][4][65];
    __shared__ float    misc_s[3][4][64];
    __shared__ float    x_cur[16][2];
    __shared__ float    x_ring[4][16][2];
    __shared__ __align__(16) uint32_t headw_s[30*132];
    __shared__ float    hxb_s[90];
    __shared__ float    wl_s[16][NW];

    const int tid = threadIdx.x;
    const int bid = blockIdx.x;
    const int g  = bid & (NGROUPS - 1);   // all 16 roles of a group share bid%8 -> same XCD
    const int rw = bid >> 3;              // role 0..15
    int stage, idx, U, u0; role_params(rw, stage, idx, U, u0);
    const int b0 = g * BT;
    const int wave = tid >> 6, lane = tid & 63;
    const int rA = lane & 15, khalf = lane >> 4;
    const int m0 = khalf * 4;
    const int NT = U >> 2, extra = NT - 8;
    const bool nt2 = (wave < extra);
    const int nt0 = nt2 ? 2*wave : extra + wave;
    const int upg = U >> 4;
    const int gate0 = nt0 / upg, ul0 = (nt0 % upg)*16 + rA;
    const int nt1c = nt2 ? nt0 + 1 : nt0;          // clamp when unused
    const int gate1 = nt1c / upg, ul1 = (nt1c % upg)*16 + rA;

    uint64_t* hbuf64 = (uint64_t*)(wsd + OFF_HBUF) + (size_t)g * 12288;
    uint32_t* cnt = wsd + OFF_CNT + g * 448;
    const float* wsf = (const float*)wsd;

    // ---- persistent weights: B-fragments in VGPRs ----
    f16x8v wrf[32];
    if (WSPACK) {
#pragma unroll
        for (int s = 0; s < 32; ++s) {
            uint4 v = *(const uint4*)(wsd + OFF_WREG + ((size_t)(rw*32 + s)*512 + tid)*4);
            wrf[s] = __builtin_bit_cast(f16x8v, v);
        }
    } else {
#pragma unroll
        for (int s = 0; s < 32; ++s) {
            uint4 v;
            v.x = fetch_wdw(rw, tid, s, 0, Whh0, WihL, WhhL);
            v.y = fetch_wdw(rw, tid, s, 1, Whh0, WihL, WhhL);
            v.z = fetch_wdw(rw, tid, s, 2, Whh0, WihL, WhhL);
            v.w = fetch_wdw(rw, tid, s, 3, Whh0, WihL, WhhL);
            wrf[s] = __builtin_bit_cast(f16x8v, v);
        }
    }

    // ---- init LDS ----
    for (int i = tid; i < 2*16*132; i += NTHM) (&h_lds[0][0][0])[i] = 0u;
    for (int i = tid; i < 768;      i += NTHM) (&misc_s[0][0][0])[i] = wsf[OFF_MISC + rw*768 + i];
    if (stage == 0) {
        for (int i = tid; i < 30*132; i += NTHM) headw_s[i] = wsd[OFF_HEADW + idx*30*132 + i];
        for (int i = tid; i < 90;     i += NTHM) hxb_s[i]   = wsf[OFF_HXB + idx*90 + i];
    }
    float c_st0 = 0.0f, c_st1 = 0.0f;
    __syncthreads();

    const f32x4v zf4 = {0.0f, 0.0f, 0.0f, 0.0f};

    if (stage == 0) {
        // =========== stage0: L0 (+ head trailing by 3) ===========
        for (int t = 0; t <= 1002; ++t) {
            const bool doL0 = (t < T_STEPS);
            const bool doHd = (t >= 3);
            const int th = t - 3;
            const int sl = t & 3, slp = (t - 1) & 3, slh = th & 3;
            float xv = 0.0f;
            if (doL0 && tid < 32)
                xv = x[((size_t)(b0 + (tid >> 1))*T_STEPS + t)*2 + (tid & 1)];
            if (tid == 0) {
                if (doL0 && t >= 1) pollCnt(PCC(0), 4u*(uint32_t)t);
                if (doL0 && t >= 4) { pollCnt(ACC_(0, sl), 4u*(uint32_t)(t >> 2));
                                      pollCnt(ACC_(1, sl), 6u*(uint32_t)(t >> 2)); }
                if (doHd)           pollCnt(PCC(2), 6u*(uint32_t)(t - 2));
            }
            __syncthreads();
            if (doL0 && t >= 1) READH(0, 0, slp)    // h0@(t-1)
            if (doHd)           READH(1, 2, slh)    // h2@(t-3)
            __syncthreads();
            if (tid == 0) {
                if (doL0 && t >= 1) bump(ACC_(0, slp));
                if (doHd)           bump(ACC_(5, slh));
            }
            if (doL0) {
                f32x4v ac0 = zf4, ac1 = zf4;
                mfma8<0>(ac0, ac1, wrf, &h_lds[0][0][0], rA, khalf, nt2);
                DWRITE()
                if (tid < 32) {
                    x_cur[tid >> 1][tid & 1] = xv;
                    x_ring[sl][tid >> 1][tid & 1] = xv;
                }
            }
            __syncthreads();
            if (doL0) {
                UPDATE_PASS(0, c_st0, 0, sl)
                UPDATE_PASS(1, c_st1, 0, sl)
            }
            __syncthreads();
            if (tid == 0 && doL0) bump(PCC(0));
            if (doHd) HEAD_COMPUTE(th, slh)
        }
    } else {
        // =========== stage1 / stage2 ===========
        const int OWN_L = stage, IN_L = stage - 1;
        const int ownCls  = (stage == 1) ? 2 : 4;
        const int own2Cls = (stage == 1) ? 3 : 5;
        const int inCls   = (stage == 1) ? 1 : 3;
        const uint32_t OTH = (stage == 1) ? 6u : 4u;
        const uint32_t PIN = (stage == 1) ? 4u : 6u;
        for (int t = 0; t < T_STEPS; ++t) {
            const int sl = t & 3, slp = (t - 1) & 3;
            float xv = 0.0f;
            if (tid < 32)
                xv = x[((size_t)(b0 + (tid >> 1))*T_STEPS + t)*2 + (tid & 1)];
            if (tid == 0) {
                if (t >= 1) pollCnt(PCC(OWN_L), 6u*(uint32_t)t);
                if (t >= 4) { pollCnt(ACC_(ownCls, sl), 6u*(uint32_t)(t >> 2));
                              pollCnt(ACC_(own2Cls, sl), OTH*(uint32_t)(t >> 2)); }
            }
            __syncthreads();
            if (t >= 1) READH(1, OWN_L, slp)
            __syncthreads();
            if (tid == 0 && t >= 1) bump(ACC_(ownCls, slp));
            f32x4v ac0 = zf4, ac1 = zf4;
            mfma8<8>(ac0, ac1, wrf, &h_lds[1][0][0], rA, khalf, nt2);   // recur first
            if (tid == 0) pollCnt(PCC(IN_L), PIN*(uint32_t)(t + 1));    // skip input h@t
            __syncthreads();
            READH(0, IN_L, sl)
            __syncthreads();
            if (tid == 0) bump(ACC_(inCls, sl));
            mfma8<0>(ac0, ac1, wrf, &h_lds[0][0][0], rA, khalf, nt2);   // skip matrix
            DWRITE()
            if (tid < 32) x_cur[tid >> 1][tid & 1] = xv;
            __syncthreads();
            UPDATE_PASS(0, c_st0, OWN_L, sl)
            UPDATE_PASS(1, c_st1, OWN_L, sl)
            __syncthreads();
            if (tid == 0) bump(PCC(OWN_L));
        }
    }
}

extern "C" void kernel_launch(void* const* d_in, const int* in_sizes, int n_in,
                              void* d_out, int out_size, void* d_ws, size_t ws_size,
                              hipStream_t stream) {
    const float* x    = (const float*)d_in[0];
    const float* Wih0 = (const float*)d_in[1];
    const float* Whh0 = (const float*)d_in[2];
    const float* bih0 = (const float*)d_in[3];
    const float* bhh0 = (const float*)d_in[4];
    const float* WihL = (const float*)d_in[5];
    const float* WhhL = (const float*)d_in[6];
    const float* bihL = (const float*)d_in[7];
    const float* bhhL = (const float*)d_in[8];
    const float* Wg   = (const float*)d_in[9];
    const float* bg   = (const float*)d_in[10];
    const float* Ww   = (const float*)d_in[11];
    const float* bw   = (const float*)d_in[12];
    float*    out = (float*)d_out;
    uint32_t* wsd = (uint32_t*)d_ws;
    (void)in_sizes; (void)n_in; (void)out_size;

    const bool wspack = ws_size >= WS_DW * 4;

    zero_cnt<<<14, 256, 0, stream>>>(wsd);
    pack_misc<<<48, 256, 0, stream>>>(Wih0, bih0, bhh0, WihL, bihL, bhhL, wsd);
    pack_head<<<64, 256, 0, stream>>>(Wg, bg, Ww, bw, wsd);
    if (wspack)
        pack_wreg<<<16*32, 512, 0, stream>>>(Whh0, WihL, WhhL, wsd);

    dim3 grid(NGROUPS * 16), block(NTHM);
    void* args[] = {(void*)&x, (void*)&wsd, (void*)&out,
                    (void*)&Whh0, (void*)&WihL, (void*)&WhhL};
    if (wspack) {
        hipError_t err = hipLaunchCooperativeKernel((const void*)lstm_pipe<true>,
                                                    grid, block, args, 0, stream);
        if (err != hipSuccess)
            lstm_pipe<true><<<grid, block, 0, stream>>>(x, wsd, out, Whh0, WihL, WhhL);
    } else {
        hipError_t err = hipLaunchCooperativeKernel((const void*)lstm_pipe<false>,
                                                    grid, block, args, 0, stream);
        if (err != hipSuccess)
            lstm_pipe<false><<<grid, block, 0, stream>>>(x, wsd, out, Whh0, WihL, WhhL);
    }
}

// Round 10
// 4568.204 us; speedup vs baseline: 1.4490x; 1.0611x over previous
//
#include <hip/hip_runtime.h>
#include <hip/hip_fp16.h>
#include <stdint.h>

// ---------------- problem constants ----------------
#define T_STEPS 1000
#define G4      1024
#define NOUT    100
#define NW      20
#define NTHM    512
#define NGROUPS 8       // batch groups of 16 rows
#define NROLE   12      // 0-3 stage0(L0+head), 4-7 stage1, 8-11 stage2; U=64 each
#define BT      16

// ---------------- ws layout (dword offsets) ----------------
// hbuf: [8 groups][3 layers][4 slots][16 rows][64 u64]
constexpr int    OFF_HBUF  = 0;
constexpr int    OFF_CNT   = OFF_HBUF + NGROUPS*3*4*16*128;  // 196608: [8][448]
constexpr int    OFF_HEADW = OFF_CNT + NGROUPS*448;          // 200192: [120][132]
constexpr int    OFF_HXB   = OFF_HEADW + 120*132;            // 216032: [120][3] f32
constexpr int    OFF_MISC  = OFF_HXB + 360;                  // 216392: [12 roles][3][4][64] f32
constexpr int    OFF_WREG  = OFF_MISC + NROLE*768;           // 225608: [12 roles][32 slots][512 thr][4dw]
constexpr size_t WS_DW     = (size_t)OFF_WREG + (size_t)NROLE*32*512*4;  // 1,012,040 dw ~= 4.05 MB
constexpr size_t GOFF      = (size_t)128*1000*100;

__device__ __forceinline__ float sigf(float x)     { return 1.0f / (1.0f + __expf(-x)); }
__device__ __forceinline__ float tanhfast(float x) { return 2.0f / (1.0f + __expf(-2.0f * x)) - 1.0f; }

typedef _Float16 h2v    __attribute__((ext_vector_type(2)));
typedef _Float16 f16x8v __attribute__((ext_vector_type(8)));
typedef float    f32x4v __attribute__((ext_vector_type(4)));
#define MFMA16(A, B, C) __builtin_amdgcn_mfma_f32_16x16x32_f16((A), (B), (C), 0, 0, 0)

__device__ __forceinline__ float dot2f(uint32_t w, uint32_t h, float acc) {
    return __builtin_amdgcn_fdot2(__builtin_bit_cast(h2v, w),
                                  __builtin_bit_cast(h2v, h), acc, false);
}
__device__ __forceinline__ uint32_t pk(float a, float b) {
    __half2 h = __floats2half2_rn(a, b);
    return *reinterpret_cast<uint32_t*>(&h);
}

__device__ __forceinline__ void role_params(int rw, int& stage, int& idx, int& U, int& u0) {
    stage = rw >> 2; idx = rw & 3; U = 64; u0 = 64*idx;
}

// B-fragment weight dword (role rw, thread tid, slot = ntl*16+kt, dword d).
// wave=tid>>6, lane=tid&63; nt = 2*wave+ntl (NT=16).
// j = gate*256 + u0 + usub*16 + (lane&15); k = [kt or kt-8]*32 + (lane>>4)*8 + 2d.
// kt<8: stage0 Whh0 / stage1,2 skip Wih; kt>=8: recur Whh (stage0 unused -> 0).
__device__ __forceinline__ uint32_t fetch_wdw(int rw, int tid, int slot, int d,
                                              const float* __restrict__ Whh0,
                                              const float* __restrict__ WihL,
                                              const float* __restrict__ WhhL) {
    int stage, idx, U, u0; role_params(rw, stage, idx, U, u0);
    int wave = tid >> 6, lane = tid & 63;
    int ntl = slot >> 4, kt = slot & 15;
    int nt = 2*wave + ntl;
    if (stage == 0 && kt >= 8) return 0u;
    int gate = nt >> 2, usub = nt & 3;
    int j = gate*256 + u0 + usub*16 + (lane & 15);
    int khalf = lane >> 4;
    if (stage == 0) {
        int k = kt*32 + khalf*8 + 2*d;
        return pk(Whh0[(size_t)j*256 + k], Whh0[(size_t)j*256 + k + 1]);
    }
    if (kt < 8) {
        int k = kt*32 + khalf*8 + 2*d;
        const float* Wi = WihL + (size_t)(stage-1)*G4*258;
        return pk(Wi[(size_t)j*258 + 2 + k], Wi[(size_t)j*258 + 3 + k]);
    }
    int k = (kt-8)*32 + khalf*8 + 2*d;
    const float* Wh = WhhL + (size_t)(stage-1)*G4*256;
    return pk(Wh[(size_t)j*256 + k], Wh[(size_t)j*256 + k + 1]);
}

// ---------------- prep kernels ----------------
__global__ void pack_wreg(const float* __restrict__ Whh0, const float* __restrict__ WihL,
                          const float* __restrict__ WhhL, uint32_t* __restrict__ wsd) {
    int slot = blockIdx.x & 31, rw = blockIdx.x >> 5;   // grid 12*32
    int tid = threadIdx.x;
    uint32_t* dst = wsd + OFF_WREG + ((size_t)(rw*32 + slot)*512 + tid)*4;
    dst[0] = fetch_wdw(rw, tid, slot, 0, Whh0, WihL, WhhL);
    dst[1] = fetch_wdw(rw, tid, slot, 1, Whh0, WihL, WhhL);
    dst[2] = fetch_wdw(rw, tid, slot, 2, Whh0, WihL, WhhL);
    dst[3] = fetch_wdw(rw, tid, slot, 3, Whh0, WihL, WhhL);
}

__global__ void pack_misc(const float* __restrict__ Wih0,
                          const float* __restrict__ bih0, const float* __restrict__ bhh0,
                          const float* __restrict__ WihL,
                          const float* __restrict__ bihL, const float* __restrict__ bhhL,
                          uint32_t* __restrict__ wsd) {
    int id = blockIdx.x * blockDim.x + threadIdx.x;
    if (id >= NROLE*768) return;
    int rw = id / 768, i = id % 768;
    int qq = i / 256, rem = i % 256, gate = rem / 64, u = rem % 64;
    int stage, idx, U, u0; role_params(rw, stage, idx, U, u0);
    int j = gate*256 + u0 + u;
    float v;
    if (stage == 0)      v = (qq == 0) ? bih0[j] + bhh0[j] : Wih0[j*2 + (qq-1)];
    else if (stage == 1) v = (qq == 0) ? bihL[j] + bhhL[j] : WihL[(size_t)j*258 + (qq-1)];
    else                 v = (qq == 0) ? bihL[G4+j] + bhhL[G4+j]
                                       : WihL[(size_t)G4*258 + (size_t)j*258 + (qq-1)];
    ((float*)wsd)[OFF_MISC + id] = v;
}

__global__ void pack_head(const float* __restrict__ Wg, const float* __restrict__ bg,
                          const float* __restrict__ Ww, const float* __restrict__ bw,
                          uint32_t* __restrict__ wsd) {
    int id = blockIdx.x * blockDim.x + threadIdx.x;
    if (id < 120*132) {
        int jo = id / 132, d = id % 132;
        uint32_t v = 0;
        if (d < 128) {
            int k = 2*d;
            const float* row = (jo < 100) ? (Wg + (size_t)jo*258) : (Ww + (size_t)(jo-100)*258);
            v = pk(row[2+k], row[3+k]);
        }
        wsd[OFF_HEADW + id] = v;
    } else if (id < 120*132 + 360) {
        int p = id - 120*132, jo = p/3, qq = p%3;
        const float* row = (jo < 100) ? (Wg + (size_t)jo*258) : (Ww + (size_t)(jo-100)*258);
        float v = (qq == 0) ? ((jo < 100) ? bg[jo] : bw[jo-100]) : row[qq-1];
        ((float*)wsd)[OFF_HXB + p] = v;
    }
}

__global__ void zero_cnt(uint32_t* __restrict__ wsd) {
    int id = blockIdx.x * blockDim.x + threadIdx.x;
    if (id < NGROUPS*448) wsd[OFF_CNT + id] = 0;
}

// ---------------- sync primitives (r8/r9 protocol, 4 readers/class) ----------------
__device__ __forceinline__ void pollCnt(uint32_t* c, uint32_t tgt) {
    int spins = 0;
    while (__hip_atomic_load(c, __ATOMIC_RELAXED, __HIP_MEMORY_SCOPE_AGENT) < tgt) {
        __builtin_amdgcn_s_sleep(1);
        if (++spins > (1 << 24)) break;   // bailout: loud wrong answer beats a hang
    }
}
__device__ __forceinline__ void bump(uint32_t* c) {
    __hip_atomic_fetch_add(c, 1u, __ATOMIC_RELAXED, __HIP_MEMORY_SCOPE_AGENT);
}
// PC_l at l*16; AC[class][slot] at (3+class*4+slot)*16
// classes: 0=h0-own(4) 1=h0-skip(4) 2=h1-own(4) 3=h1-skip(4) 4=h2-own(4) 5=h2-head(4)
#define PCC(L)     (cnt + (L)*16)
#define ACC_(C, S) (cnt + (3 + (C)*4 + (S))*16)

// 8 MFMA k-steps over one 256-wide h operand (padded LDS rows of 132 dw)
template<int SO>
__device__ __forceinline__ void mfma8(f32x4v& ac0, f32x4v& ac1, const f16x8v (&wrf)[32],
                                      const uint32_t* hb, int rA, int khalf) {
#pragma unroll
    for (int kt = 0; kt < 8; ++kt) {
        uint4 hv = *(const uint4*)(hb + rA*132 + kt*16 + khalf*4);
        f16x8v a = __builtin_bit_cast(f16x8v, hv);
        ac0 = MFMA16(a, wrf[SO + kt], ac0);
        ac1 = MFMA16(a, wrf[16 + SO + kt], ac1);
    }
}

#define READH(BUF, L, SLOT)                                                        \
    { _Pragma("unroll")                                                            \
      for (int p_ = 0; p_ < 2; ++p_) {                                             \
        int idx_ = tid + p_*512;                                                   \
        int r_ = idx_ >> 6, i_ = idx_ & 63;                                        \
        uint64_t v_ = __hip_atomic_load(hbuf64 + (((L)*4 + (SLOT))*16 + r_)*64 + i_, \
                                        __ATOMIC_RELAXED, __HIP_MEMORY_SCOPE_AGENT); \
        *(uint64_t*)&h_lds[BUF][r_][2*i_] = v_;                                    \
      } }

#define DWRITE()                                                                   \
    { _Pragma("unroll")                                                            \
      for (int rg = 0; rg < 4; ++rg) g_s[m0 + rg][gate0][ul0] = ac0[rg];           \
      _Pragma("unroll")                                                            \
      for (int rg = 0; rg < 4; ++rg) g_s[m0 + rg][gate1][ul1] = ac1[rg]; }

#define UPDATE_PASS(PASS, CST, LYR, SLOT)                                          \
    { int r_ = tid & 15, u_ = (PASS)*32 + (tid >> 4);                              \
      float x0 = x_cur[r_][0], x1 = x_cur[r_][1];                                  \
      float gi = g_s[r_][0][u_] + misc_s[0][0][u_] + x0*misc_s[1][0][u_] + x1*misc_s[2][0][u_]; \
      float gf = g_s[r_][1][u_] + misc_s[0][1][u_] + x0*misc_s[1][1][u_] + x1*misc_s[2][1][u_]; \
      float gg = g_s[r_][2][u_] + misc_s[0][2][u_] + x0*misc_s[1][2][u_] + x1*misc_s[2][2][u_]; \
      float go = g_s[r_][3][u_] + misc_s[0][3][u_] + x0*misc_s[1][3][u_] + x1*misc_s[2][3][u_]; \
      float cc_ = sigf(gf)*(CST) + sigf(gi)*tanhfast(gg);                          \
      float hval = sigf(go)*tanhfast(cc_);  (CST) = cc_;                           \
      float h1_ = __shfl_down(hval, 16), h2_ = __shfl_down(hval, 32), h3_ = __shfl_down(hval, 48); \
      if ((tid & 63) < 16) {                                                       \
          uint64_t pv = (uint64_t)pk(hval, h1_) | ((uint64_t)pk(h2_, h3_) << 32);  \
          __hip_atomic_store(hbuf64 + (((LYR)*4 + (SLOT))*16 + r_)*64              \
                                 + (u0 >> 2) + (PASS)*8 + (tid >> 6), pv,          \
                             __ATOMIC_RELAXED, __HIP_MEMORY_SCOPE_AGENT);          \
      } }

#define HEAD_COMPUTE(TT, SLH)                                                      \
    { int jol = tid >> 4, rr2 = tid & 15;                                          \
      float acch = 0.0f;                                                           \
      if (jol < 30) {                                                              \
          _Pragma("unroll")                                                        \
          for (int d4 = 0; d4 < 32; ++d4) {                                        \
              uint4 wv = *(const uint4*)&headw_s[jol*132 + d4*4];                  \
              uint4 hv = *(const uint4*)&h_lds[1][rr2][d4*4];                      \
              acch = dot2f(wv.x, hv.x, acch); acch = dot2f(wv.y, hv.y, acch);      \
              acch = dot2f(wv.z, hv.z, acch); acch = dot2f(wv.w, hv.w, acch);      \
          }                                                                        \
          int jo = idx*30 + jol;                                                   \
          float xa = x_ring[SLH][rr2][0], xb = x_ring[SLH][rr2][1];                \
          acch += hxb_s[jol*3] + xa*hxb_s[jol*3+1] + xb*hxb_s[jol*3+2];            \
          if (jo < NOUT) out[((size_t)(b0 + rr2)*T_STEPS + (TT))*NOUT + jo] = acch; \
          else           wl_s[rr2][jo - NOUT] = acch;                              \
      }                                                                            \
      __syncthreads();                                                             \
      if (idx == 3 && tid < 16) {                                                  \
          int r = tid;                                                             \
          float mx = -1e30f;                                                       \
          _Pragma("unroll")                                                        \
          for (int m = 0; m < NW; ++m) mx = fmaxf(mx, wl_s[r][m]);                 \
          float ss = 0.0f, ee[NW];                                                 \
          _Pragma("unroll")                                                        \
          for (int m = 0; m < NW; ++m) { ee[m] = __expf(wl_s[r][m] - mx); ss += ee[m]; } \
          float inv = 1.0f / ss;                                                   \
          size_t bo = GOFF + ((size_t)(b0 + r)*T_STEPS + (TT))*NW;                 \
          _Pragma("unroll")                                                        \
          for (int m = 0; m < NW; ++m) out[bo + m] = ee[m]*inv;                    \
      } }

template <bool WSPACK>
__global__ __launch_bounds__(NTHM, 1)
void lstm_pipe(const float* __restrict__ x, uint32_t* __restrict__ wsd,
               float* __restrict__ out,
               const float* __restrict__ Whh0, const float* __restrict__ WihL,
               const float* __restrict__ WhhL) {
    __shared__ __align__(16) uint32_t h_lds[2][16][132];   // fp16-pair dw, padded stride
    __shared__ float    g_s[16][4][65];
    __shared__ float    misc_s[3][4][64];
    __shared__ float    x_cur[16][2];
    __shared__ float    x_ring[4][16][2];
    __shared__ __align__(16) uint32_t headw_s[30*132];
    __shared__ float    hxb_s[90];
    __shared__ float    wl_s[16][NW];

    const int tid = threadIdx.x;
    const int bid = blockIdx.x;
    const int g  = bid & (NGROUPS - 1);   // same g -> bids differ by 8 -> same XCD
    const int rw = bid >> 3;              // role 0..11
    int stage, idx, U, u0; role_params(rw, stage, idx, U, u0);
    const int b0 = g * BT;
    const int wave = tid >> 6, lane = tid & 63;
    const int rA = lane & 15, khalf = lane >> 4;
    const int m0 = khalf * 4;
    const int nt0 = 2*wave, nt1 = 2*wave + 1;
    const int gate0 = nt0 >> 2, ul0 = (nt0 & 3)*16 + rA;
    const int gate1 = nt1 >> 2, ul1 = (nt1 & 3)*16 + rA;

    uint64_t* hbuf64 = (uint64_t*)(wsd + OFF_HBUF) + (size_t)g * 12288;
    uint32_t* cnt = wsd + OFF_CNT + g * 448;
    const float* wsf = (const float*)wsd;

    // ---- persistent weights: B-fragments in VGPRs ----
    f16x8v wrf[32];
    if (WSPACK) {
#pragma unroll
        for (int s = 0; s < 32; ++s) {
            uint4 v = *(const uint4*)(wsd + OFF_WREG + ((size_t)(rw*32 + s)*512 + tid)*4);
            wrf[s] = __builtin_bit_cast(f16x8v, v);
        }
    } else {
#pragma unroll
        for (int s = 0; s < 32; ++s) {
            uint4 v;
            v.x = fetch_wdw(rw, tid, s, 0, Whh0, WihL, WhhL);
            v.y = fetch_wdw(rw, tid, s, 1, Whh0, WihL, WhhL);
            v.z = fetch_wdw(rw, tid, s, 2, Whh0, WihL, WhhL);
            v.w = fetch_wdw(rw, tid, s, 3, Whh0, WihL, WhhL);
            wrf[s] = __builtin_bit_cast(f16x8v, v);
        }
    }

    // ---- init LDS ----
    for (int i = tid; i < 2*16*132; i += NTHM) (&h_lds[0][0][0])[i] = 0u;
    for (int i = tid; i < 768;      i += NTHM) (&misc_s[0][0][0])[i] = wsf[OFF_MISC + rw*768 + i];
    if (stage == 0) {
        for (int i = tid; i < 30*132; i += NTHM) headw_s[i] = wsd[OFF_HEADW + idx*30*132 + i];
        for (int i = tid; i < 90;     i += NTHM) hxb_s[i]   = wsf[OFF_HXB + idx*90 + i];
    }
    float c_st0 = 0.0f, c_st1 = 0.0f;
    __syncthreads();

    const f32x4v zf4 = {0.0f, 0.0f, 0.0f, 0.0f};

    if (stage == 0) {
        // ===== stage0: L0 publishes FIRST; head (t-3) strictly after the post =====
        for (int t = 0; t <= 1002; ++t) {
            const bool doL0 = (t < T_STEPS);
            const bool doHd = (t >= 3);
            const int th = t - 3;
            const int sl = t & 3, slp = (t - 1) & 3, slh = th & 3;
            float xv = 0.0f;
            if (doL0 && tid < 32)
                xv = x[((size_t)(b0 + (tid >> 1))*T_STEPS + t)*2 + (tid & 1)];
            if (tid == 0 && doL0) {
                if (t >= 1) pollCnt(PCC(0), 4u*(uint32_t)t);
                if (t >= 4) { pollCnt(ACC_(0, sl), 4u*(uint32_t)(t >> 2));
                              pollCnt(ACC_(1, sl), 4u*(uint32_t)(t >> 2)); }
            }
            __syncthreads();
            if (doL0 && t >= 1) READH(0, 0, slp)        // h0@(t-1)
            __syncthreads();
            if (tid == 0 && doL0 && t >= 1) bump(ACC_(0, slp));
            if (doL0) {
                f32x4v ac0 = zf4, ac1 = zf4;
                mfma8<0>(ac0, ac1, wrf, &h_lds[0][0][0], rA, khalf);
                DWRITE()
                if (tid < 32) {
                    x_cur[tid >> 1][tid & 1] = xv;
                    x_ring[sl][tid >> 1][tid & 1] = xv;
                }
            }
            __syncthreads();
            if (doL0) {
                UPDATE_PASS(0, c_st0, 0, sl)
                UPDATE_PASS(1, c_st1, 0, sl)
            }
            __syncthreads();
            if (tid == 0 && doL0) bump(PCC(0));         // h0@t published
            // ---- head phase (off the publish path) ----
            if (doHd) {
                if (tid == 0) pollCnt(PCC(2), 4u*(uint32_t)(t - 2));
                __syncthreads();
                READH(1, 2, slh)                        // h2@(t-3)
                __syncthreads();
                if (tid == 0) bump(ACC_(5, slh));
                HEAD_COMPUTE(th, slh)
            }
        }
    } else {
        // ===== stage1 / stage2: SKIP-FIRST, own-recurrence hidden behind it =====
        const int OWN_L = stage, IN_L = stage - 1;
        const int ownCls  = (stage == 1) ? 2 : 4;
        const int own2Cls = (stage == 1) ? 3 : 5;
        const int inCls   = (stage == 1) ? 1 : 3;
        for (int t = 0; t < T_STEPS; ++t) {
            const int sl = t & 3, slp = (t - 1) & 3;
            float xv = 0.0f;
            if (tid < 32)
                xv = x[((size_t)(b0 + (tid >> 1))*T_STEPS + t)*2 + (tid & 1)];
            if (tid == 0) {
                pollCnt(PCC(IN_L), 4u*(uint32_t)(t + 1));              // skip input h@t (aged)
                if (t >= 4) { pollCnt(ACC_(ownCls, sl), 4u*(uint32_t)(t >> 2));
                              pollCnt(ACC_(own2Cls, sl), 4u*(uint32_t)(t >> 2)); }
            }
            __syncthreads();
            READH(0, IN_L, sl)                                         // h_{l-1}@t
            __syncthreads();
            if (tid == 0) bump(ACC_(inCls, sl));
            f32x4v ac0 = zf4, ac1 = zf4;
            mfma8<0>(ac0, ac1, wrf, &h_lds[0][0][0], rA, khalf);       // skip matrix
            if (tid == 0 && t >= 1) pollCnt(PCC(OWN_L), 4u*(uint32_t)t);  // own h@t-1
            __syncthreads();
            if (t >= 1) READH(1, OWN_L, slp)
            __syncthreads();
            if (tid == 0 && t >= 1) bump(ACC_(ownCls, slp));
            mfma8<8>(ac0, ac1, wrf, &h_lds[1][0][0], rA, khalf);       // recurrent matrix
            DWRITE()
            if (tid < 32) x_cur[tid >> 1][tid & 1] = xv;
            __syncthreads();
            UPDATE_PASS(0, c_st0, OWN_L, sl)
            UPDATE_PASS(1, c_st1, OWN_L, sl)
            __syncthreads();
            if (tid == 0) bump(PCC(OWN_L));
        }
    }
}

extern "C" void kernel_launch(void* const* d_in, const int* in_sizes, int n_in,
                              void* d_out, int out_size, void* d_ws, size_t ws_size,
                              hipStream_t stream) {
    const float* x    = (const float*)d_in[0];
    const float* Wih0 = (const float*)d_in[1];
    const float* Whh0 = (const float*)d_in[2];
    const float* bih0 = (const float*)d_in[3];
    const float* bhh0 = (const float*)d_in[4];
    const float* WihL = (const float*)d_in[5];
    const float* WhhL = (const float*)d_in[6];
    const float* bihL = (const float*)d_in[7];
    const float* bhhL = (const float*)d_in[8];
    const float* Wg   = (const float*)d_in[9];
    const float* bg   = (const float*)d_in[10];
    const float* Ww   = (const float*)d_in[11];
    const float* bw   = (const float*)d_in[12];
    float*    out = (float*)d_out;
    uint32_t* wsd = (uint32_t*)d_ws;
    (void)in_sizes; (void)n_in; (void)out_size;

    const bool wspack = ws_size >= WS_DW * 4;

    zero_cnt<<<14, 256, 0, stream>>>(wsd);
    pack_misc<<<36, 256, 0, stream>>>(Wih0, bih0, bhh0, WihL, bihL, bhhL, wsd);
    pack_head<<<64, 256, 0, stream>>>(Wg, bg, Ww, bw, wsd);
    if (wspack)
        pack_wreg<<<NROLE*32, 512, 0, stream>>>(Whh0, WihL, WhhL, wsd);

    dim3 grid(NGROUPS * NROLE), block(NTHM);
    void* args[] = {(void*)&x, (void*)&wsd, (void*)&out,
                    (void*)&Whh0, (void*)&WihL, (void*)&WhhL};
    if (wspack) {
        hipError_t err = hipLaunchCooperativeKernel((const void*)lstm_pipe<true>,
                                                    grid, block, args, 0, stream);
        if (err != hipSuccess)
            lstm_pipe<true><<<grid, block, 0, stream>>>(x, wsd, out, Whh0, WihL, WhhL);
    } else {
        hipError_t err = hipLaunchCooperativeKernel((const void*)lstm_pipe<false>,
                                                    grid, block, args, 0, stream);
        if (err != hipSuccess)
            lstm_pipe<false><<<grid, block, 0, stream>>>(x, wsd, out, Whh0, WihL, WhhL);
    }
}

// Round 11
// 3927.926 us; speedup vs baseline: 1.6852x; 1.1630x over previous
//
#include <hip/hip_runtime.h>
#include <hip/hip_fp16.h>
#include <stdint.h>

// ---------------- problem constants ----------------
#define T_STEPS 1000
#define G4      1024
#define NOUT    100
#define NW      20
#define NTHM    512
#define NGROUPS 8       // batch groups of 16 rows
#define NROLE   12      // 0-3 stage0(L0+head), 4-7 stage1, 8-11 stage2; U=64 each
#define BT      16

// ---------------- ws layout (dword offsets) ----------------
// hbuf: [8 groups][3 layers][4 slots][16 rows][64 u64]
constexpr int    OFF_HBUF  = 0;
constexpr int    OFF_CNT   = OFF_HBUF + NGROUPS*3*4*16*128;  // 196608: [8][448] (only 3 PCs used)
constexpr int    OFF_HEADW = OFF_CNT + NGROUPS*448;          // 200192: [120][132]
constexpr int    OFF_HXB   = OFF_HEADW + 120*132;            // 216032: [120][3] f32
constexpr int    OFF_MISC  = OFF_HXB + 360;                  // 216392: [12 roles][3][4][64] f32
constexpr int    OFF_WREG  = OFF_MISC + NROLE*768;           // 225608: [12 roles][32 slots][512 thr][4dw]
constexpr size_t WS_DW     = (size_t)OFF_WREG + (size_t)NROLE*32*512*4;  // ~4.05 MB
constexpr size_t GOFF      = (size_t)128*1000*100;

__device__ __forceinline__ float sigf(float x)     { return 1.0f / (1.0f + __expf(-x)); }
__device__ __forceinline__ float tanhfast(float x) { return 2.0f / (1.0f + __expf(-2.0f * x)) - 1.0f; }

typedef _Float16 h2v    __attribute__((ext_vector_type(2)));
typedef _Float16 f16x8v __attribute__((ext_vector_type(8)));
typedef float    f32x4v __attribute__((ext_vector_type(4)));
#define MFMA16(A, B, C) __builtin_amdgcn_mfma_f32_16x16x32_f16((A), (B), (C), 0, 0, 0)

__device__ __forceinline__ float dot2f(uint32_t w, uint32_t h, float acc) {
    return __builtin_amdgcn_fdot2(__builtin_bit_cast(h2v, w),
                                  __builtin_bit_cast(h2v, h), acc, false);
}
__device__ __forceinline__ uint32_t pk(float a, float b) {
    __half2 h = __floats2half2_rn(a, b);
    return *reinterpret_cast<uint32_t*>(&h);
}

__device__ __forceinline__ void role_params(int rw, int& stage, int& idx, int& U, int& u0) {
    stage = rw >> 2; idx = rw & 3; U = 64; u0 = 64*idx;
}

// B-fragment weight dword (role rw, thread tid, slot = ntl*16+kt, dword d).
// wave=tid>>6, lane=tid&63; nt = 2*wave+ntl (NT=16).
// j = gate*256 + u0 + usub*16 + (lane&15); k = [kt or kt-8]*32 + (lane>>4)*8 + 2d.
// kt<8: stage0 Whh0 / stage1,2 skip Wih; kt>=8: recur Whh (stage0 unused -> 0).
__device__ __forceinline__ uint32_t fetch_wdw(int rw, int tid, int slot, int d,
                                              const float* __restrict__ Whh0,
                                              const float* __restrict__ WihL,
                                              const float* __restrict__ WhhL) {
    int stage, idx, U, u0; role_params(rw, stage, idx, U, u0);
    int wave = tid >> 6, lane = tid & 63;
    int ntl = slot >> 4, kt = slot & 15;
    int nt = 2*wave + ntl;
    if (stage == 0 && kt >= 8) return 0u;
    int gate = nt >> 2, usub = nt & 3;
    int j = gate*256 + u0 + usub*16 + (lane & 15);
    int khalf = lane >> 4;
    if (stage == 0) {
        int k = kt*32 + khalf*8 + 2*d;
        return pk(Whh0[(size_t)j*256 + k], Whh0[(size_t)j*256 + k + 1]);
    }
    if (kt < 8) {
        int k = kt*32 + khalf*8 + 2*d;
        const float* Wi = WihL + (size_t)(stage-1)*G4*258;
        return pk(Wi[(size_t)j*258 + 2 + k], Wi[(size_t)j*258 + 3 + k]);
    }
    int k = (kt-8)*32 + khalf*8 + 2*d;
    const float* Wh = WhhL + (size_t)(stage-1)*G4*256;
    return pk(Wh[(size_t)j*256 + k], Wh[(size_t)j*256 + k + 1]);
}

// ---------------- prep kernels ----------------
__global__ void pack_wreg(const float* __restrict__ Whh0, const float* __restrict__ WihL,
                          const float* __restrict__ WhhL, uint32_t* __restrict__ wsd) {
    int slot = blockIdx.x & 31, rw = blockIdx.x >> 5;   // grid 12*32
    int tid = threadIdx.x;
    uint32_t* dst = wsd + OFF_WREG + ((size_t)(rw*32 + slot)*512 + tid)*4;
    dst[0] = fetch_wdw(rw, tid, slot, 0, Whh0, WihL, WhhL);
    dst[1] = fetch_wdw(rw, tid, slot, 1, Whh0, WihL, WhhL);
    dst[2] = fetch_wdw(rw, tid, slot, 2, Whh0, WihL, WhhL);
    dst[3] = fetch_wdw(rw, tid, slot, 3, Whh0, WihL, WhhL);
}

__global__ void pack_misc(const float* __restrict__ Wih0,
                          const float* __restrict__ bih0, const float* __restrict__ bhh0,
                          const float* __restrict__ WihL,
                          const float* __restrict__ bihL, const float* __restrict__ bhhL,
                          uint32_t* __restrict__ wsd) {
    int id = blockIdx.x * blockDim.x + threadIdx.x;
    if (id >= NROLE*768) return;
    int rw = id / 768, i = id % 768;
    int qq = i / 256, rem = i % 256, gate = rem / 64, u = rem % 64;
    int stage, idx, U, u0; role_params(rw, stage, idx, U, u0);
    int j = gate*256 + u0 + u;
    float v;
    if (stage == 0)      v = (qq == 0) ? bih0[j] + bhh0[j] : Wih0[j*2 + (qq-1)];
    else if (stage == 1) v = (qq == 0) ? bihL[j] + bhhL[j] : WihL[(size_t)j*258 + (qq-1)];
    else                 v = (qq == 0) ? bihL[G4+j] + bhhL[G4+j]
                                       : WihL[(size_t)G4*258 + (size_t)j*258 + (qq-1)];
    ((float*)wsd)[OFF_MISC + id] = v;
}

__global__ void pack_head(const float* __restrict__ Wg, const float* __restrict__ bg,
                          const float* __restrict__ Ww, const float* __restrict__ bw,
                          uint32_t* __restrict__ wsd) {
    int id = blockIdx.x * blockDim.x + threadIdx.x;
    if (id < 120*132) {
        int jo = id / 132, d = id % 132;
        uint32_t v = 0;
        if (d < 128) {
            int k = 2*d;
            const float* row = (jo < 100) ? (Wg + (size_t)jo*258) : (Ww + (size_t)(jo-100)*258);
            v = pk(row[2+k], row[3+k]);
        }
        wsd[OFF_HEADW + id] = v;
    } else if (id < 120*132 + 360) {
        int p = id - 120*132, jo = p/3, qq = p%3;
        const float* row = (jo < 100) ? (Wg + (size_t)jo*258) : (Ww + (size_t)(jo-100)*258);
        float v = (qq == 0) ? ((jo < 100) ? bg[jo] : bw[jo-100]) : row[qq-1];
        ((float*)wsd)[OFF_HXB + p] = v;
    }
}

__global__ void zero_cnt(uint32_t* __restrict__ wsd) {
    int id = blockIdx.x * blockDim.x + threadIdx.x;
    if (id < NGROUPS*448) wsd[OFF_CNT + id] = 0;
}

// ---------------- sync primitives: PC counters ONLY ----------------
// Ack-free safety: head dependency bounds stage0 <= stage2+3; data deps bound
// stage1 <= stage0, stage2 <= stage1 -> pipeline spread <= 3 beats < ring-4.
// Verified slot-by-slot: no ring-4 slot is overwritten while a reader within
// the 3-beat window can still need it.
__device__ __forceinline__ void pollCnt(uint32_t* c, uint32_t tgt) {
    int spins = 0;
    while (__hip_atomic_load(c, __ATOMIC_RELAXED, __HIP_MEMORY_SCOPE_AGENT) < tgt) {
        __builtin_amdgcn_s_sleep(1);
        if (++spins > (1 << 24)) break;   // bailout: loud wrong answer beats a hang
    }
}
__device__ __forceinline__ void bump(uint32_t* c) {
    __hip_atomic_fetch_add(c, 1u, __ATOMIC_RELAXED, __HIP_MEMORY_SCOPE_AGENT);
}
#define PCC(L) (cnt + (L)*16)

// 8 MFMA k-steps over one 256-wide h operand (padded LDS rows of 132 dw)
template<int SO>
__device__ __forceinline__ void mfma8(f32x4v& ac0, f32x4v& ac1, const f16x8v (&wrf)[32],
                                      const uint32_t* hb, int rA, int khalf) {
#pragma unroll
    for (int kt = 0; kt < 8; ++kt) {
        uint4 hv = *(const uint4*)(hb + rA*132 + kt*16 + khalf*4);
        f16x8v a = __builtin_bit_cast(f16x8v, hv);
        ac0 = MFMA16(a, wrf[SO + kt], ac0);
        ac1 = MFMA16(a, wrf[16 + SO + kt], ac1);
    }
}

#define READH(BUF, L, SLOT)                                                        \
    { _Pragma("unroll")                                                            \
      for (int p_ = 0; p_ < 2; ++p_) {                                             \
        int idx_ = tid + p_*512;                                                   \
        int r_ = idx_ >> 6, i_ = idx_ & 63;                                        \
        uint64_t v_ = __hip_atomic_load(hbuf64 + (((L)*4 + (SLOT))*16 + r_)*64 + i_, \
                                        __ATOMIC_RELAXED, __HIP_MEMORY_SCOPE_AGENT); \
        *(uint64_t*)&h_lds[BUF][r_][2*i_] = v_;                                    \
      } }

#define DWRITE()                                                                   \
    { _Pragma("unroll")                                                            \
      for (int rg = 0; rg < 4; ++rg) g_s[m0 + rg][gate0][ul0] = ac0[rg];           \
      _Pragma("unroll")                                                            \
      for (int rg = 0; rg < 4; ++rg) g_s[m0 + rg][gate1][ul1] = ac1[rg]; }

#define UPDATE_PASS(PASS, CST, LYR, SLOT)                                          \
    { int r_ = tid & 15, u_ = (PASS)*32 + (tid >> 4);                              \
      float x0 = x_cur[r_][0], x1 = x_cur[r_][1];                                  \
      float gi = g_s[r_][0][u_] + misc_s[0][0][u_] + x0*misc_s[1][0][u_] + x1*misc_s[2][0][u_]; \
      float gf = g_s[r_][1][u_] + misc_s[0][1][u_] + x0*misc_s[1][1][u_] + x1*misc_s[2][1][u_]; \
      float gg = g_s[r_][2][u_] + misc_s[0][2][u_] + x0*misc_s[1][2][u_] + x1*misc_s[2][2][u_]; \
      float go = g_s[r_][3][u_] + misc_s[0][3][u_] + x0*misc_s[1][3][u_] + x1*misc_s[2][3][u_]; \
      float cc_ = sigf(gf)*(CST) + sigf(gi)*tanhfast(gg);                          \
      float hval = sigf(go)*tanhfast(cc_);  (CST) = cc_;                           \
      float h1_ = __shfl_down(hval, 16), h2_ = __shfl_down(hval, 32), h3_ = __shfl_down(hval, 48); \
      if ((tid & 63) < 16) {                                                       \
          uint64_t pv = (uint64_t)pk(hval, h1_) | ((uint64_t)pk(h2_, h3_) << 32);  \
          __hip_atomic_store(hbuf64 + (((LYR)*4 + (SLOT))*16 + r_)*64              \
                                 + (u0 >> 2) + (PASS)*8 + (tid >> 6), pv,          \
                             __ATOMIC_RELAXED, __HIP_MEMORY_SCOPE_AGENT);          \
      } }

#define HEAD_COMPUTE(TT, SLH)                                                      \
    { int jol = tid >> 4, rr2 = tid & 15;                                          \
      float acch = 0.0f;                                                           \
      if (jol < 30) {                                                              \
          _Pragma("unroll")                                                        \
          for (int d4 = 0; d4 < 32; ++d4) {                                        \
              uint4 wv = *(const uint4*)&headw_s[jol*132 + d4*4];                  \
              uint4 hv = *(const uint4*)&h_lds[1][rr2][d4*4];                      \
              acch = dot2f(wv.x, hv.x, acch); acch = dot2f(wv.y, hv.y, acch);      \
              acch = dot2f(wv.z, hv.z, acch); acch = dot2f(wv.w, hv.w, acch);      \
          }                                                                        \
          int jo = idx*30 + jol;                                                   \
          float xa = x_ring[SLH][rr2][0], xb = x_ring[SLH][rr2][1];                \
          acch += hxb_s[jol*3] + xa*hxb_s[jol*3+1] + xb*hxb_s[jol*3+2];            \
          if (jo < NOUT) out[((size_t)(b0 + rr2)*T_STEPS + (TT))*NOUT + jo] = acch; \
          else           wl_s[rr2][jo - NOUT] = acch;                              \
      }                                                                            \
      __syncthreads();                                                             \
      if (idx == 3 && tid < 16) {                                                  \
          int r = tid;                                                             \
          float mx = -1e30f;                                                       \
          _Pragma("unroll")                                                        \
          for (int m = 0; m < NW; ++m) mx = fmaxf(mx, wl_s[r][m]);                 \
          float ss = 0.0f, ee[NW];                                                 \
          _Pragma("unroll")                                                        \
          for (int m = 0; m < NW; ++m) { ee[m] = __expf(wl_s[r][m] - mx); ss += ee[m]; } \
          float inv = 1.0f / ss;                                                   \
          size_t bo = GOFF + ((size_t)(b0 + r)*T_STEPS + (TT))*NW;                 \
          _Pragma("unroll")                                                        \
          for (int m = 0; m < NW; ++m) out[bo + m] = ee[m]*inv;                    \
      } }

template <bool WSPACK>
__global__ __launch_bounds__(NTHM, 1)
void lstm_pipe(const float* __restrict__ x, uint32_t* __restrict__ wsd,
               float* __restrict__ out,
               const float* __restrict__ Whh0, const float* __restrict__ WihL,
               const float* __restrict__ WhhL) {
    __shared__ __align__(16) uint32_t h_lds[2][16][132];   // fp16-pair dw, padded stride
    __shared__ float    g_s[16][4][65];
    __shared__ float    misc_s[3][4][64];
    __shared__ float    x_cur[16][2];
    __shared__ float    x_ring[4][16][2];
    __shared__ __align__(16) uint32_t headw_s[30*132];
    __shared__ float    hxb_s[90];
    __shared__ float    wl_s[16][NW];

    const int tid = threadIdx.x;
    const int bid = blockIdx.x;
    const int g  = bid & (NGROUPS - 1);   // same g -> bids differ by 8 -> same XCD
    const int rw = bid >> 3;              // role 0..11
    int stage, idx, U, u0; role_params(rw, stage, idx, U, u0);
    const int b0 = g * BT;
    const int wave = tid >> 6, lane = tid & 63;
    const int rA = lane & 15, khalf = lane >> 4;
    const int m0 = khalf * 4;
    const int nt0 = 2*wave, nt1 = 2*wave + 1;
    const int gate0 = nt0 >> 2, ul0 = (nt0 & 3)*16 + rA;
    const int gate1 = nt1 >> 2, ul1 = (nt1 & 3)*16 + rA;

    uint64_t* hbuf64 = (uint64_t*)(wsd + OFF_HBUF) + (size_t)g * 12288;
    uint32_t* cnt = wsd + OFF_CNT + g * 448;
    const float* wsf = (const float*)wsd;

    // ---- persistent weights: B-fragments in VGPRs ----
    f16x8v wrf[32];
    if (WSPACK) {
#pragma unroll
        for (int s = 0; s < 32; ++s) {
            uint4 v = *(const uint4*)(wsd + OFF_WREG + ((size_t)(rw*32 + s)*512 + tid)*4);
            wrf[s] = __builtin_bit_cast(f16x8v, v);
        }
    } else {
#pragma unroll
        for (int s = 0; s < 32; ++s) {
            uint4 v;
            v.x = fetch_wdw(rw, tid, s, 0, Whh0, WihL, WhhL);
            v.y = fetch_wdw(rw, tid, s, 1, Whh0, WihL, WhhL);
            v.z = fetch_wdw(rw, tid, s, 2, Whh0, WihL, WhhL);
            v.w = fetch_wdw(rw, tid, s, 3, Whh0, WihL, WhhL);
            wrf[s] = __builtin_bit_cast(f16x8v, v);
        }
    }

    // ---- init LDS ----
    for (int i = tid; i < 2*16*132; i += NTHM) (&h_lds[0][0][0])[i] = 0u;
    for (int i = tid; i < 768;      i += NTHM) (&misc_s[0][0][0])[i] = wsf[OFF_MISC + rw*768 + i];
    if (stage == 0) {
        for (int i = tid; i < 30*132; i += NTHM) headw_s[i] = wsd[OFF_HEADW + idx*30*132 + i];
        for (int i = tid; i < 90;     i += NTHM) hxb_s[i]   = wsf[OFF_HXB + idx*90 + i];
    }
    float c_st0 = 0.0f, c_st1 = 0.0f;
    __syncthreads();

    const f32x4v zf4 = {0.0f, 0.0f, 0.0f, 0.0f};

    if (stage == 0) {
        // ===== stage0: L0 publishes first; head (t-3) strictly after the post =====
        for (int t = 0; t <= 1002; ++t) {
            const bool doL0 = (t < T_STEPS);
            const bool doHd = (t >= 3);
            const int th = t - 3;
            const int sl = t & 3, slp = (t - 1) & 3, slh = th & 3;
            float xv = 0.0f;
            if (doL0 && tid < 32)
                xv = x[((size_t)(b0 + (tid >> 1))*T_STEPS + t)*2 + (tid & 1)];
            if (tid == 0 && doL0 && t >= 1) pollCnt(PCC(0), 4u*(uint32_t)t);
            __syncthreads();
            if (doL0 && t >= 1) READH(0, 0, slp)        // h0@(t-1)
            if (doL0 && tid < 32) {
                x_cur[tid >> 1][tid & 1] = xv;
                x_ring[sl][tid >> 1][tid & 1] = xv;
            }
            __syncthreads();
            if (doL0) {
                f32x4v ac0 = zf4, ac1 = zf4;
                mfma8<0>(ac0, ac1, wrf, &h_lds[0][0][0], rA, khalf);
                DWRITE()
            }
            __syncthreads();
            if (doL0) {
                UPDATE_PASS(0, c_st0, 0, sl)
                UPDATE_PASS(1, c_st1, 0, sl)
            }
            __syncthreads();
            if (tid == 0 && doL0) bump(PCC(0));         // h0@t published
            // ---- head phase (off the publish path; bounds stage0 lead <= 3) ----
            if (doHd) {
                if (tid == 0) pollCnt(PCC(2), 4u*(uint32_t)(t - 2));
                __syncthreads();
                READH(1, 2, slh)                        // h2@(t-3)
                __syncthreads();
                HEAD_COMPUTE(th, slh)
            }
        }
    } else {
        // ===== stage1 / stage2: fused dual-read, minimal protocol =====
        const int OWN_L = stage, IN_L = stage - 1;
        for (int t = 0; t < T_STEPS; ++t) {
            const int sl = t & 3, slp = (t - 1) & 3;
            float xv = 0.0f;
            if (tid < 32)
                xv = x[((size_t)(b0 + (tid >> 1))*T_STEPS + t)*2 + (tid & 1)];
            if (tid == 0) {
                if (t >= 1) pollCnt(PCC(OWN_L), 4u*(uint32_t)t);       // own h@t-1
                pollCnt(PCC(IN_L), 4u*(uint32_t)(t + 1));              // skip input h@t
            }
            __syncthreads();
            READH(0, IN_L, sl)                                         // both reads issued
            if (t >= 1) READH(1, OWN_L, slp)                           //   back-to-back
            if (tid < 32) x_cur[tid >> 1][tid & 1] = xv;
            __syncthreads();
            f32x4v ac0 = zf4, ac1 = zf4;
            mfma8<0>(ac0, ac1, wrf, &h_lds[0][0][0], rA, khalf);       // skip matrix
            mfma8<8>(ac0, ac1, wrf, &h_lds[1][0][0], rA, khalf);       // recurrent matrix
            DWRITE()
            __syncthreads();
            UPDATE_PASS(0, c_st0, OWN_L, sl)
            UPDATE_PASS(1, c_st1, OWN_L, sl)
            __syncthreads();
            if (tid == 0) bump(PCC(OWN_L));
        }
    }
}

extern "C" void kernel_launch(void* const* d_in, const int* in_sizes, int n_in,
                              void* d_out, int out_size, void* d_ws, size_t ws_size,
                              hipStream_t stream) {
    const float* x    = (const float*)d_in[0];
    const float* Wih0 = (const float*)d_in[1];
    const float* Whh0 = (const float*)d_in[2];
    const float* bih0 = (const float*)d_in[3];
    const float* bhh0 = (const float*)d_in[4];
    const float* WihL = (const float*)d_in[5];
    const float* WhhL = (const float*)d_in[6];
    const float* bihL = (const float*)d_in[7];
    const float* bhhL = (const float*)d_in[8];
    const float* Wg   = (const float*)d_in[9];
    const float* bg   = (const float*)d_in[10];
    const float* Ww   = (const float*)d_in[11];
    const float* bw   = (const float*)d_in[12];
    float*    out = (float*)d_out;
    uint32_t* wsd = (uint32_t*)d_ws;
    (void)in_sizes; (void)n_in; (void)out_size;

    const bool wspack = ws_size >= WS_DW * 4;

    zero_cnt<<<14, 256, 0, stream>>>(wsd);
    pack_misc<<<36, 256, 0, stream>>>(Wih0, bih0, bhh0, WihL, bihL, bhhL, wsd);
    pack_head<<<64, 256, 0, stream>>>(Wg, bg, Ww, bw, wsd);
    if (wspack)
        pack_wreg<<<NROLE*32, 512, 0, stream>>>(Whh0, WihL, WhhL, wsd);

    dim3 grid(NGROUPS * NROLE), block(NTHM);
    void* args[] = {(void*)&x, (void*)&wsd, (void*)&out,
                    (void*)&Whh0, (void*)&WihL, (void*)&WhhL};
    if (wspack) {
        hipError_t err = hipLaunchCooperativeKernel((const void*)lstm_pipe<true>,
                                                    grid, block, args, 0, stream);
        if (err != hipSuccess)
            lstm_pipe<true><<<grid, block, 0, stream>>>(x, wsd, out, Whh0, WihL, WhhL);
    } else {
        hipError_t err = hipLaunchCooperativeKernel((const void*)lstm_pipe<false>,
                                                    grid, block, args, 0, stream);
        if (err != hipSuccess)
            lstm_pipe<false><<<grid, block, 0, stream>>>(x, wsd, out, Whh0, WihL, WhhL);
    }
}